// Round 1
// 1005.616 us; speedup vs baseline: 1.1075x; 1.1075x over previous
//
#include <hip/hip_runtime.h>
#include <hip/hip_bf16.h>

// QuantizedLinear: out[b,s,o] = sum_i x[b,s,i] * (code[q[o,i]] * absmax[o]) + bias[o]
// M = 4096, K = 4096, N = 16384. absmax index == o because in_features == BLOCK.
//
// Path: dequant W -> bf16 (ws), convert x -> bf16 (ws), then 256x256 8-phase
// counted-vmcnt bf16 MFMA GEMM (T1+T2+T3+T4+T5 stack, per m194-m201 template).

typedef __bf16 bf16x8 __attribute__((ext_vector_type(8)));
typedef __bf16 bf16x4 __attribute__((ext_vector_type(4)));
typedef float  f32x4  __attribute__((ext_vector_type(4)));

#define GLD_LDS(gp, lp) \
    __builtin_amdgcn_global_load_lds((const __attribute__((address_space(1))) void*)(gp), \
                                     (__attribute__((address_space(3))) void*)(lp), 16, 0, 0)

static constexpr int M = 4096;
static constexpr int N = 16384;
static constexpr int K = 4096;
static constexpr int BM = 256;
static constexpr int BN = 256;
static constexpr int BK = 64;
static constexpr int NT = K / BK;                       // 64 K-tiles
static constexpr int LDS_BYTES = 2 * 2 * 256 * BK * 2;  // 128 KiB (2 dbuf x {A,B} x 256x64 bf16)

// ---------------------------------------------------------------- dequant W
// W_bf16[o*K + i] = bf16(code[q[o*K+i]] * absmax[o]); 4 elems/thread.
// code[] gathers go through LDS (1 KB table) instead of 4 random VMEM gathers —
// frees the L1/TA port for the streaming int4 reads.
__global__ __launch_bounds__(256) void dequant_w(const int4* __restrict__ q4,
                                                 const float* __restrict__ code,
                                                 const float* __restrict__ absmax,
                                                 bf16x4* __restrict__ W)
{
    __shared__ float lc[256];
    lc[threadIdx.x] = code[threadIdx.x];
    __syncthreads();
    unsigned gid = blockIdx.x * 256u + threadIdx.x;     // 16M threads, 4 elems each
    int4 qv = q4[gid];
    float am = absmax[gid >> 10];                       // (gid*4) / 4096
    bf16x4 w;
    w[0] = (__bf16)(lc[qv.x] * am);
    w[1] = (__bf16)(lc[qv.y] * am);
    w[2] = (__bf16)(lc[qv.z] * am);
    w[3] = (__bf16)(lc[qv.w] * am);
    W[gid] = w;
}

// ---------------------------------------------------------------- x fp32 -> bf16
__global__ __launch_bounds__(256) void cvt_x(const float4* __restrict__ x,
                                             bf16x4* __restrict__ xb)
{
    unsigned gid = blockIdx.x * 256u + threadIdx.x;     // 4M threads
    float4 v = x[gid];
    bf16x4 o;
    o[0] = (__bf16)v.x;
    o[1] = (__bf16)v.y;
    o[2] = (__bf16)v.z;
    o[3] = (__bf16)v.w;
    xb[gid] = o;
}

// ---------------------------------------------------------------- GEMM C = A @ B^T + bias
// A: M x K bf16 row-major. B: N x K bf16 row-major (= W). C: M x N fp32.
// 512 threads = 8 waves (2M x 4N); per-wave output 128x64 = acc[8][4] of 16x16 frags.
//
// LDS tile layout: [row][slot] where slot = 16B column-chunk, SWIZZLED:
//   LDS[r][s] holds global chunk (s ^ (r&7)).  Row stride 128 B == 32 banks, so
//   bank = slot; the XOR makes each 8-lane group of a frag ds_read_b128 hit 8
//   distinct slots -> conflict-free.  Staging keeps the LDS dest LINEAR (m104
//   global_load_lds constraint) and pre-permutes the GLOBAL source column.
//
// Counted-vmcnt schedule (T3+T4): tile t's 8 loads are issued as 3 halves at the
// t-1/t boundary + 1 half inside phase 1 of t-1.  At each boundary: issue 3 halves
// of t+1, then s_waitcnt vmcnt(6)  ==> retires exactly tile t's 8 loads; the 6
// newer stay in flight across the barrier.  vmcnt(0) only at the last tile.

__device__ __forceinline__ void stage_half(const __bf16* gp, char* ldsbase, int h, int tid)
{
    GLD_LDS(gp + (size_t)(h * 128) * K,      ldsbase + h * 16384 +        tid * 16);
    GLD_LDS(gp + (size_t)(h * 128 + 64) * K, ldsbase + h * 16384 + 8192 + tid * 16);
}

__device__ __forceinline__ void tile_step(const __bf16*& agn, const __bf16*& bgn,
                                          const char* cA, const char* cB,
                                          char* nA, char* nB, bool pf, int tid,
                                          int baseA, int baseB, f32x4 (&acc)[8][4])
{
    // ---- boundary: issue 3 halves of next tile, counted wait for current tile
    if (pf) {
        stage_half(agn, nA, 0, tid);
        stage_half(agn, nA, 1, tid);
        stage_half(bgn, nB, 0, tid);
        asm volatile("s_waitcnt vmcnt(6)" ::: "memory");
    } else {
        asm volatile("s_waitcnt vmcnt(0)" ::: "memory");
    }
    __builtin_amdgcn_s_barrier();

    // ---- phase 1: last half of next tile + B frags (8) + A frags mi{0,1} (4)
    if (pf) {
        stage_half(bgn, nB, 1, tid);
        agn += BK;
        bgn += BK;
    }

    bf16x8 bfr[4][2], af[2][2];
#pragma unroll
    for (int ni = 0; ni < 4; ++ni) {
        bfr[ni][0] = *(const bf16x8*)(cB + (baseB + ni * 2048));
        bfr[ni][1] = *(const bf16x8*)(cB + ((baseB + ni * 2048) ^ 64));   // kk=1 flips slot bit 2
    }
    af[0][0] = *(const bf16x8*)(cA + baseA);
    af[0][1] = *(const bf16x8*)(cA + (baseA ^ 64));
    af[1][0] = *(const bf16x8*)(cA + (baseA + 2048));
    af[1][1] = *(const bf16x8*)(cA + ((baseA + 2048) ^ 64));

    __builtin_amdgcn_s_barrier();
    __builtin_amdgcn_s_setprio(1);
#pragma unroll
    for (int kk = 0; kk < 2; ++kk)
#pragma unroll
        for (int i = 0; i < 2; ++i)
#pragma unroll
            for (int ni = 0; ni < 4; ++ni)
                acc[i][ni] = __builtin_amdgcn_mfma_f32_16x16x32_bf16(
                    af[i][kk], bfr[ni][kk], acc[i][ni], 0, 0, 0);
    __builtin_amdgcn_s_setprio(0);
    __builtin_amdgcn_s_barrier();

    // ---- phases 2..4: A frags mi{2p,2p+1}, 16 MFMA each
#pragma unroll
    for (int p = 1; p < 4; ++p) {
        af[0][0] = *(const bf16x8*)(cA + (baseA + (2 * p) * 2048));
        af[0][1] = *(const bf16x8*)(cA + ((baseA + (2 * p) * 2048) ^ 64));
        af[1][0] = *(const bf16x8*)(cA + (baseA + (2 * p + 1) * 2048));
        af[1][1] = *(const bf16x8*)(cA + ((baseA + (2 * p + 1) * 2048) ^ 64));
        __builtin_amdgcn_s_barrier();
        __builtin_amdgcn_s_setprio(1);
#pragma unroll
        for (int kk = 0; kk < 2; ++kk)
#pragma unroll
            for (int i = 0; i < 2; ++i)
#pragma unroll
                for (int ni = 0; ni < 4; ++ni)
                    acc[2 * p + i][ni] = __builtin_amdgcn_mfma_f32_16x16x32_bf16(
                        af[i][kk], bfr[ni][kk], acc[2 * p + i][ni], 0, 0, 0);
        __builtin_amdgcn_s_setprio(0);
        __builtin_amdgcn_s_barrier();
    }
}

__global__ __launch_bounds__(512, 2) void gemm_bt_bias(const __bf16* __restrict__ A,
                                                       const __bf16* __restrict__ B,
                                                       const float* __restrict__ bias,
                                                       float* __restrict__ C)
{
    extern __shared__ char lds[];
    const int tid  = threadIdx.x;
    const int lane = tid & 63;
    const int wave = tid >> 6;
    const int wm = wave >> 2;                 // 0..1  (M direction)
    const int wn = wave & 3;                  // 0..3  (N direction)

    // T1: bijective XCD swizzle (nwg = 1024, %8 == 0), m-fastest so each XCD's
    // 128 blocks share 8 B-panels (B-panel L2 reuse) and all of A (L3).
    const int cpx  = (int)gridDim.x >> 3;
    const int flat = ((int)blockIdx.x & 7) * cpx + ((int)blockIdx.x >> 3);
    const int bm = (flat & (M / BM - 1)) * BM;
    const int bn = (flat / (M / BM)) * BN;

    // staging map: thread covers LDS rows (tid>>3) + {0,64} per half, slot tid&7.
    // pre-swizzled global source chunk = slot ^ (row&7)  (row&7 == (tid>>3)&7 for both loads)
    const int r0 = tid >> 3;
    const int cs = (tid & 7) ^ (r0 & 7);
    const __bf16* ag = A + (size_t)(bm + r0) * K + cs * 8;
    const __bf16* bg = B + (size_t)(bn + r0) * K + cs * 8;

    char* const ldsA0 = lds;
    char* const ldsB0 = lds + 32768;
    char* const ldsA1 = lds + 65536;
    char* const ldsB1 = lds + 98304;

    // frag read base: row = w*{128,64} + (lane&15), slot = ((lane>>4)|kk<<2) ^ (lane&7)
    const int swz   = ((lane >> 4) ^ (lane & 7)) << 4;
    const int baseA = (wm * 128 + (lane & 15)) * 128 + swz;
    const int baseB = (wn * 64  + (lane & 15)) * 128 + swz;

    f32x4 acc[8][4] = {};

    // prologue: tile 0 fully staged into buf0 (8 loads)
    stage_half(ag, ldsA0, 0, tid);
    stage_half(ag, ldsA0, 1, tid);
    stage_half(bg, ldsB0, 0, tid);
    stage_half(bg, ldsB0, 1, tid);

    const __bf16* agn = ag + BK;
    const __bf16* bgn = bg + BK;

    for (int t2 = 0; t2 < NT; t2 += 2) {
        tile_step(agn, bgn, ldsA0, ldsB0, ldsA1, ldsB1, true,         tid, baseA, baseB, acc);
        tile_step(agn, bgn, ldsA1, ldsB1, ldsA0, ldsB0, t2 + 2 < NT,  tid, baseA, baseB, acc);
    }

    // epilogue: D[m=(lane>>4)*4+reg][n=lane&15] (verified m89/m91 mapping)
    const int cn = lane & 15;
    const int rq = (lane >> 4) * 4;
#pragma unroll
    for (int ni = 0; ni < 4; ++ni) {
        const int n = bn + wn * 64 + ni * 16 + cn;
        const float bv = bias[n];
#pragma unroll
        for (int mi = 0; mi < 8; ++mi) {
#pragma unroll
            for (int r = 0; r < 4; ++r) {
                const int m = bm + wm * 128 + mi * 16 + rq + r;
                C[(size_t)m * N + n] = acc[mi][ni][r] + bv;
            }
        }
    }
}

extern "C" void kernel_launch(void* const* d_in, const int* in_sizes, int n_in,
                              void* d_out, int out_size, void* d_ws, size_t ws_size,
                              hipStream_t stream)
{
    const float* x      = (const float*)d_in[0];   // 2*2048*4096 fp32
    const int*   qw     = (const int*)d_in[1];     // 16384*4096 int32
    const float* absmax = (const float*)d_in[2];   // 16384 fp32
    const float* code   = (const float*)d_in[3];   // 256 fp32
    const float* bias   = (const float*)d_in[4];   // 16384 fp32
    float* out = (float*)d_out;                    // 4096 x 16384 fp32

    // workspace: W_bf16 (N*K*2 = 128 MB) then x_bf16 (M*K*2 = 32 MB)
    __bf16* Wb = (__bf16*)d_ws;
    __bf16* Xb = (__bf16*)((char*)d_ws + (size_t)N * K * sizeof(__bf16));

    static bool attr_set = false;
    if (!attr_set) {
        (void)hipFuncSetAttribute((const void*)gemm_bt_bias,
                                  hipFuncAttributeMaxDynamicSharedMemorySize, LDS_BYTES);
        attr_set = true;
    }

    // dequant: N*K/4 = 16M work-items
    dequant_w<<<(N * (long long)K) / 4 / 256, 256, 0, stream>>>(
        (const int4*)qw, code, absmax, (bf16x4*)Wb);

    // x convert: M*K/4 = 4M work-items
    cvt_x<<<(M * (long long)K) / 4 / 256, 256, 0, stream>>>(
        (const float4*)x, (bf16x4*)Xb);

    // GEMM: (M/BM)*(N/BN) = 16*64 = 1024 blocks, 512 threads, 128 KiB dynamic LDS
    gemm_bt_bias<<<dim3((M / BM) * (N / BN)), dim3(512), LDS_BYTES, stream>>>(
        Xb, Wb, bias, out);
}

// Round 2
// 994.083 us; speedup vs baseline: 1.1204x; 1.0116x over previous
//
#include <hip/hip_runtime.h>
#include <hip/hip_bf16.h>

// QuantizedLinear: out[b,s,o] = sum_i x[b,s,i] * (code[q[o,i]] * absmax[o]) + bias[o]
// M = 4096, K = 4096, N = 16384. absmax index == o because in_features == BLOCK.
//
// Round 2: GEMM reworked to a 1-barrier-per-phase counted-vmcnt schedule
// (4 phases/K-tile, uniform vmcnt(4), stage order A-h0,B-h0,B-h1,A-h1 with
// wave-relative halves; publish lag = 2 phases, verified hazard table).
// dequant/cvt switched to 2048-block grid-stride (dispatch-overhead theory).

typedef __bf16 bf16x8 __attribute__((ext_vector_type(8)));
typedef float  f32x4  __attribute__((ext_vector_type(4)));

#define GLD_LDS(gp, lp) \
    __builtin_amdgcn_global_load_lds((const __attribute__((address_space(1))) void*)(gp), \
                                     (__attribute__((address_space(3))) void*)(lp), 16, 0, 0)

static constexpr int M = 4096;
static constexpr int N = 16384;
static constexpr int K = 4096;
static constexpr int BM = 256;
static constexpr int BN = 256;
static constexpr int BK = 64;
static constexpr int NT = K / BK;                       // 64 K-tiles
static constexpr int LDS_BYTES = 131072;                // 2 dbuf x {A,B} x 256x64 bf16

// ---------------------------------------------------------------- dequant W
// W_bf16[o*K + i] = bf16(code[q[o*K+i]] * absmax[o]); 8 elems/thread, grid-stride.
__global__ __launch_bounds__(256) void dequant_w(const int4* __restrict__ q4,
                                                 const float* __restrict__ code,
                                                 const float* __restrict__ absmax,
                                                 bf16x8* __restrict__ W)
{
    __shared__ float lc[256];
    lc[threadIdx.x] = code[threadIdx.x];
    __syncthreads();
    const unsigned total  = (unsigned)((unsigned long long)N * K / 8);   // 8.4M
    const unsigned stride = gridDim.x * 256u;
    for (unsigned gid = blockIdx.x * 256u + threadIdx.x; gid < total; gid += stride) {
        int4 q0 = q4[2u * gid];
        int4 q1 = q4[2u * gid + 1u];
        float am = absmax[gid >> 9];                    // (gid*8) / 4096
        bf16x8 w;
        w[0] = (__bf16)(lc[q0.x] * am);
        w[1] = (__bf16)(lc[q0.y] * am);
        w[2] = (__bf16)(lc[q0.z] * am);
        w[3] = (__bf16)(lc[q0.w] * am);
        w[4] = (__bf16)(lc[q1.x] * am);
        w[5] = (__bf16)(lc[q1.y] * am);
        w[6] = (__bf16)(lc[q1.z] * am);
        w[7] = (__bf16)(lc[q1.w] * am);
        W[gid] = w;
    }
}

// ---------------------------------------------------------------- x fp32 -> bf16
__global__ __launch_bounds__(256) void cvt_x(const float4* __restrict__ x,
                                             bf16x8* __restrict__ xb)
{
    const unsigned total  = (unsigned)((unsigned long long)M * K / 8);   // 2.1M
    const unsigned stride = gridDim.x * 256u;
    for (unsigned gid = blockIdx.x * 256u + threadIdx.x; gid < total; gid += stride) {
        float4 a = x[2u * gid];
        float4 b = x[2u * gid + 1u];
        bf16x8 o;
        o[0] = (__bf16)a.x; o[1] = (__bf16)a.y; o[2] = (__bf16)a.z; o[3] = (__bf16)a.w;
        o[4] = (__bf16)b.x; o[5] = (__bf16)b.y; o[6] = (__bf16)b.z; o[7] = (__bf16)b.w;
        xb[gid] = o;
    }
}

// ---------------------------------------------------------------- GEMM C = A @ B^T + bias
// 512 threads = 8 waves (2M x 4N); per-wave output 128x64 = acc[8][4] 16x16 frags.
//
// LDS halves are WAVE-RELATIVE so each phase's reads touch only published halves:
//   A-h = per-wave rows h*64..h*64+63  -> physical lds row l = h*128 + wm*64 + r
//   B-h = per-wave rows h*32..h*32+31  -> physical lds row l = h*128 + wn*32 + r
// XOR swizzle (slot ^= row&7) as round 1: stage keeps LDS dest linear and
// pre-permutes the GLOBAL source chunk; reads apply the same XOR. (conflict=0)
//
// Per K-tile t: 4 phases, each {stage 2 loads of t+1 ; ds_reads ; vmcnt(4) ;
// barrier ; setprio(1) 16 MFMA setprio(0)}.  Stage order [A-h0,B-h0,B-h1,A-h1];
// vmcnt(4) retires the stage issued 2 phases earlier; the barrier publishes it
// one phase before its first read (hazard table verified).  Reads per phase:
// ph0: A-mh0(8)+B-nh0(4), ph1: B-nh1(4), ph2: A-mh1(8)+B-nh0(4), ph3: B-nh1(4)
// (B re-read per phase to keep frag regs at 48 VGPR -> 2 waves/SIMD budget).

template<int MH, int NH>
__device__ __forceinline__ void mfma_quad(f32x4 (&acc)[8][4],
                                          const bf16x8 (&af)[4][2],
                                          const bf16x8 (&bf)[2][2])
{
    __builtin_amdgcn_s_setprio(1);
#pragma unroll
    for (int kk = 0; kk < 2; ++kk)
#pragma unroll
        for (int mi = 0; mi < 4; ++mi)
#pragma unroll
            for (int ni = 0; ni < 2; ++ni)
                acc[MH * 4 + mi][NH * 2 + ni] = __builtin_amdgcn_mfma_f32_16x16x32_bf16(
                    af[mi][kk], bf[ni][kk], acc[MH * 4 + mi][NH * 2 + ni], 0, 0, 0);
    __builtin_amdgcn_s_setprio(0);
}

__global__ __launch_bounds__(512, 2) void gemm_bt_bias(const __bf16* __restrict__ A,
                                                       const __bf16* __restrict__ B,
                                                       const float* __restrict__ bias,
                                                       float* __restrict__ C)
{
    extern __shared__ char lds[];
    const int tid  = threadIdx.x;
    const int lane = tid & 63;
    const int wave = tid >> 6;
    const int wm = wave >> 2;                 // 0..1  (M direction)
    const int wn = wave & 3;                  // 0..3  (N direction)

    // T1: bijective XCD swizzle (nwg=1024), m-fastest: each XCD's 128 blocks
    // share 8 B-panels (L2 reuse) and all of A (L3).
    const int cpx  = (int)gridDim.x >> 3;
    const int flat = ((int)blockIdx.x & 7) * cpx + ((int)blockIdx.x >> 3);
    const int bm = (flat & (M / BM - 1)) * BM;
    const int bn = (flat / (M / BM)) * BN;

    // staging map: thread covers lds row r0 = tid>>3 within a 64-row group,
    // slot tid&7; source chunk pre-permuted: cs = (tid&7) ^ (r0&7).
    const int r0 = tid >> 3;
    const int cs = (tid & 7) ^ (r0 & 7);
    const int b_r0 = (r0 & 31) + (r0 >> 5) * 64;

    const __bf16* ag = A + (size_t)(bm + r0) * K + cs * 8;
    const __bf16* bg = B + (size_t)(bn + b_r0) * K + cs * 8;

    char* const ldsA0 = lds;
    char* const ldsB0 = lds + 32768;
    char* const ldsA1 = lds + 65536;
    char* const ldsB1 = lds + 98304;
    const int ldst = tid * 16;

    // A stage (h,q): global row bm + h*64 + q*128 + r0 -> lds l = h*128+q*64+r0
    auto stageA = [&](char* dst, int h, size_t kn) {
        GLD_LDS(ag + kn + (size_t)(h * 64) * K,       dst + h * 16384 + ldst);
        GLD_LDS(ag + kn + (size_t)(h * 64 + 128) * K, dst + h * 16384 + 8192 + ldst);
    };
    // B stage (h,q): global row bn + b_r0 + h*32 + q*128 -> lds l = h*128+q*64+r0
    auto stageB = [&](char* dst, int h, size_t kn) {
        GLD_LDS(bg + kn + (size_t)(h * 32) * K,       dst + h * 16384 + ldst);
        GLD_LDS(bg + kn + (size_t)(h * 32 + 128) * K, dst + h * 16384 + 8192 + ldst);
    };

    // frag reads: A l = mh*128 + wm*64 + mi*16 + fr; B l = nh*128 + wn*32 + ni*16 + fr
    // slot = ((lane>>4) | kk<<2) ^ (lane&7); kk flips byte bit6 (addr ^ 64).
    const int fr  = lane & 15;
    const int swz = ((lane >> 4) ^ (lane & 7)) << 4;
    const int aoff = (wm * 64 + fr) * 128 + swz;
    const int boff = (wn * 32 + fr) * 128 + swz;

    auto loadA = [&](const char* cA, int mh, bf16x8 (&af)[4][2]) {
        const int base = mh * 16384 + aoff;
#pragma unroll
        for (int mi = 0; mi < 4; ++mi) {
            af[mi][0] = *(const bf16x8*)(cA + (base + mi * 2048));
            af[mi][1] = *(const bf16x8*)(cA + ((base + mi * 2048) ^ 64));
        }
    };
    auto loadB = [&](const char* cB, int nh, bf16x8 (&bf)[2][2]) {
        const int base = nh * 16384 + boff;
#pragma unroll
        for (int ni = 0; ni < 2; ++ni) {
            bf[ni][0] = *(const bf16x8*)(cB + (base + ni * 2048));
            bf[ni][1] = *(const bf16x8*)(cB + ((base + ni * 2048) ^ 64));
        }
    };

    f32x4 acc[8][4] = {};

    // prologue: tile 0 fully staged (consumption order), retire oldest 4, publish
    stageA(ldsA0, 0, 0);
    stageB(ldsB0, 0, 0);
    stageB(ldsB0, 1, 0);
    stageA(ldsA0, 1, 0);
    asm volatile("s_waitcnt vmcnt(4)" ::: "memory");
    __builtin_amdgcn_s_barrier();

    auto tile_body = [&](const char* cA, const char* cB, char* nA, char* nB,
                         bool pf, size_t kn) {
        bf16x8 af[4][2], bf[2][2];
        // ---- phase 0: quadrant (0,0)
        if (pf) stageA(nA, 0, kn);
        loadA(cA, 0, af);
        loadB(cB, 0, bf);
        if (pf) asm volatile("s_waitcnt vmcnt(4)" ::: "memory");
        else    asm volatile("s_waitcnt vmcnt(0)" ::: "memory");
        __builtin_amdgcn_s_barrier();
        mfma_quad<0, 0>(acc, af, bf);
        // ---- phase 1: quadrant (0,1)
        if (pf) stageB(nB, 0, kn);
        loadB(cB, 1, bf);
        if (pf) {
            asm volatile("s_waitcnt vmcnt(4)" ::: "memory");
            __builtin_amdgcn_s_barrier();
        }
        mfma_quad<0, 1>(acc, af, bf);
        // ---- phase 2: quadrant (1,0)
        if (pf) stageB(nB, 1, kn);
        loadA(cA, 1, af);
        loadB(cB, 0, bf);
        if (pf) {
            asm volatile("s_waitcnt vmcnt(4)" ::: "memory");
            __builtin_amdgcn_s_barrier();
        }
        mfma_quad<1, 0>(acc, af, bf);
        // ---- phase 3: quadrant (1,1)
        if (pf) stageA(nA, 1, kn);
        loadB(cB, 1, bf);
        if (pf) {
            asm volatile("s_waitcnt vmcnt(4)" ::: "memory");
            __builtin_amdgcn_s_barrier();
        }
        mfma_quad<1, 1>(acc, af, bf);
    };

    for (int t = 0; t < NT; t += 2) {
        tile_body(ldsA0, ldsB0, ldsA1, ldsB1, true,        (size_t)(t + 1) * BK);
        tile_body(ldsA1, ldsB1, ldsA0, ldsB0, t + 2 < NT,  (size_t)(t + 2) * BK);
    }

    // epilogue: D[m=(lane>>4)*4+reg][n=lane&15] (verified m89/m91 mapping)
    const int cn = lane & 15;
    const int rq = (lane >> 4) * 4;
#pragma unroll
    for (int ni = 0; ni < 4; ++ni) {
        const int n = bn + wn * 64 + ni * 16 + cn;
        const float bv = bias[n];
#pragma unroll
        for (int mi = 0; mi < 8; ++mi) {
#pragma unroll
            for (int r = 0; r < 4; ++r) {
                const int m = bm + wm * 128 + mi * 16 + rq + r;
                C[(size_t)m * N + n] = acc[mi][ni][r] + bv;
            }
        }
    }
}

extern "C" void kernel_launch(void* const* d_in, const int* in_sizes, int n_in,
                              void* d_out, int out_size, void* d_ws, size_t ws_size,
                              hipStream_t stream)
{
    const float* x      = (const float*)d_in[0];   // 2*2048*4096 fp32
    const int*   qw     = (const int*)d_in[1];     // 16384*4096 int32
    const float* absmax = (const float*)d_in[2];   // 16384 fp32
    const float* code   = (const float*)d_in[3];   // 256 fp32
    const float* bias   = (const float*)d_in[4];   // 16384 fp32
    float* out = (float*)d_out;                    // 4096 x 16384 fp32

    // workspace: W_bf16 (N*K*2 = 128 MB) then x_bf16 (M*K*2 = 32 MB)
    __bf16* Wb = (__bf16*)d_ws;
    __bf16* Xb = (__bf16*)((char*)d_ws + (size_t)N * K * sizeof(__bf16));

    static bool attr_set = false;
    if (!attr_set) {
        (void)hipFuncSetAttribute((const void*)gemm_bt_bias,
                                  hipFuncAttributeMaxDynamicSharedMemorySize, LDS_BYTES);
        attr_set = true;
    }

    // dequant + cvt: capped grids, grid-stride (G11 - dispatch overhead)
    dequant_w<<<2048, 256, 0, stream>>>((const int4*)qw, code, absmax, (bf16x8*)Wb);
    cvt_x<<<2048, 256, 0, stream>>>((const float4*)x, (bf16x8*)Xb);

    // GEMM: 16*64 = 1024 blocks, 512 threads, 128 KiB dynamic LDS
    gemm_bt_bias<<<dim3((M / BM) * (N / BN)), dim3(512), LDS_BYTES, stream>>>(
        Xb, Wb, bias, out);
}

// Round 3
// 992.556 us; speedup vs baseline: 1.1221x; 1.0015x over previous
//
#include <hip/hip_runtime.h>
#include <hip/hip_bf16.h>

// QuantizedLinear: out[b,s,o] = sum_i x[b,s,i] * (code[q[o,i]] * absmax[o]) + bias[o]
// M = 4096, K = 4096, N = 16384. absmax index == o because in_features == BLOCK.
//
// Round 3: GEMM keeps all B frags register-resident per K-tile (24 ds_read_b128
// per wave per tile, the minimum for the 2Mx4N wave grid) and runs 2 barriers
// per tile (4 sub-phases; mid vmcnt(4), end vmcnt(2) — hazard table verified).
// dequant/cvt reverted to flat grids (round-2 grid-stride measured -73 us).

typedef __bf16 bf16x8 __attribute__((ext_vector_type(8)));
typedef float  f32x4  __attribute__((ext_vector_type(4)));

#define GLD_LDS(gp, lp) \
    __builtin_amdgcn_global_load_lds((const __attribute__((address_space(1))) void*)(gp), \
                                     (__attribute__((address_space(3))) void*)(lp), 16, 0, 0)

static constexpr int M = 4096;
static constexpr int N = 16384;
static constexpr int K = 4096;
static constexpr int BM = 256;
static constexpr int BN = 256;
static constexpr int BK = 64;
static constexpr int NT = K / BK;                       // 64 K-tiles
static constexpr int LDS_BYTES = 131072;                // 2 dbuf x {A,B} x 256x64 bf16

// ---------------------------------------------------------------- dequant W
// W_bf16[o*K + i] = bf16(code[q[o*K+i]] * absmax[o]); 8 elems/thread, FLAT grid.
__global__ __launch_bounds__(256) void dequant_w(const int4* __restrict__ q4,
                                                 const float* __restrict__ code,
                                                 const float* __restrict__ absmax,
                                                 bf16x8* __restrict__ W)
{
    __shared__ float lc[256];
    lc[threadIdx.x] = code[threadIdx.x];
    __syncthreads();
    unsigned gid = blockIdx.x * 256u + threadIdx.x;     // 8.4M threads
    int4 q0 = q4[2u * gid];
    int4 q1 = q4[2u * gid + 1u];
    float am = absmax[gid >> 9];                        // (gid*8) / 4096
    bf16x8 w;
    w[0] = (__bf16)(lc[q0.x] * am);
    w[1] = (__bf16)(lc[q0.y] * am);
    w[2] = (__bf16)(lc[q0.z] * am);
    w[3] = (__bf16)(lc[q0.w] * am);
    w[4] = (__bf16)(lc[q1.x] * am);
    w[5] = (__bf16)(lc[q1.y] * am);
    w[6] = (__bf16)(lc[q1.z] * am);
    w[7] = (__bf16)(lc[q1.w] * am);
    W[gid] = w;
}

// ---------------------------------------------------------------- x fp32 -> bf16
__global__ __launch_bounds__(256) void cvt_x(const float4* __restrict__ x,
                                             bf16x8* __restrict__ xb)
{
    unsigned gid = blockIdx.x * 256u + threadIdx.x;     // 2.1M threads
    float4 a = x[2u * gid];
    float4 b = x[2u * gid + 1u];
    bf16x8 o;
    o[0] = (__bf16)a.x; o[1] = (__bf16)a.y; o[2] = (__bf16)a.z; o[3] = (__bf16)a.w;
    o[4] = (__bf16)b.x; o[5] = (__bf16)b.y; o[6] = (__bf16)b.z; o[7] = (__bf16)b.w;
    xb[gid] = o;
}

// ---------------------------------------------------------------- GEMM C = A @ B^T + bias
// 512 threads = 8 waves (2M x 4N); per-wave output 128x64 = acc[8][4] 16x16 frags.
//
// LDS layout, XOR swizzle, staging map, frag maps: identical to round 2 (passed,
// bank-conflict = 0).  Schedule per K-tile t (staging for t+1):
//   region 1: [stageB h0 | loadB ALL(8) + loadA(h0,k0)(4) | 16 MFMA]
//             [stageB h1 | loadA(h0,k1)(4)                | 16 MFMA]
//             vmcnt(4)  barrier  sched_barrier(0)
//   region 2: [stageA h0 | loadA(h1,k0)(4)                | 16 MFMA]
//             [stageA h1 | loadA(h1,k1)(4)                | 16 MFMA]
//             vmcnt(2)  barrier  sched_barrier(0)
// vmcnt table (2 loads per stage): at mid-barrier outstanding = {t-1:Ah1}+{t:Bh0,Bh1}=6,
// vmcnt(4) retires t-1:Ah1 (read in region 2).  At end-barrier outstanding =
// {t:Bh0,Bh1,Ah0,Ah1}=8, vmcnt(2) retires B-all + Ah0 (read in t+1 region 1),
// leaves Ah1 in flight.  Every ds_read's last use precedes the next barrier, so
// compiler lgkm-before-MFMA makes buffer overwrite WAR-safe.

__global__ __launch_bounds__(512, 2) void gemm_bt_bias(const __bf16* __restrict__ A,
                                                       const __bf16* __restrict__ B,
                                                       const float* __restrict__ bias,
                                                       float* __restrict__ C)
{
    extern __shared__ char lds[];
    const int tid  = threadIdx.x;
    const int lane = tid & 63;
    const int wave = tid >> 6;
    const int wm = wave >> 2;                 // 0..1  (M direction)
    const int wn = wave & 3;                  // 0..3  (N direction)

    // T1: bijective XCD swizzle (nwg=1024), m-fastest: each XCD's 128 blocks
    // share 8 B-panels (L2 reuse) and all of A (L3).
    const int cpx  = (int)gridDim.x >> 3;
    const int flat = ((int)blockIdx.x & 7) * cpx + ((int)blockIdx.x >> 3);
    const int bm = (flat & (M / BM - 1)) * BM;
    const int bn = (flat / (M / BM)) * BN;

    // staging map: thread covers lds row r0 = tid>>3 within a 64-row group,
    // slot tid&7; source chunk pre-permuted: cs = (tid&7) ^ (r0&7).
    const int r0 = tid >> 3;
    const int cs = (tid & 7) ^ (r0 & 7);
    const int b_r0 = (r0 & 31) + (r0 >> 5) * 64;

    const __bf16* ag = A + (size_t)(bm + r0) * K + cs * 8;
    const __bf16* bg = B + (size_t)(bn + b_r0) * K + cs * 8;

    char* const ldsA0 = lds;
    char* const ldsB0 = lds + 32768;
    char* const ldsA1 = lds + 65536;
    char* const ldsB1 = lds + 98304;
    const int ldst = tid * 16;

    auto stageA = [&](char* dst, int h, size_t kn) {
        GLD_LDS(ag + kn + (size_t)(h * 64) * K,       dst + h * 16384 + ldst);
        GLD_LDS(ag + kn + (size_t)(h * 64 + 128) * K, dst + h * 16384 + 8192 + ldst);
    };
    auto stageB = [&](char* dst, int h, size_t kn) {
        GLD_LDS(bg + kn + (size_t)(h * 32) * K,       dst + h * 16384 + ldst);
        GLD_LDS(bg + kn + (size_t)(h * 32 + 128) * K, dst + h * 16384 + 8192 + ldst);
    };

    // frag reads: A row = mh*128 + wm*64 + mi*16 + fr; B row = nh*128 + wn*32 + ni2*16 + fr
    // slot = ((lane>>4) | kk<<2) ^ (lane&7); kk flips byte bit 6 (addr ^ 64).
    const int fr  = lane & 15;
    const int swz = ((lane >> 4) ^ (lane & 7)) << 4;
    const int aoff = (wm * 64 + fr) * 128 + swz;
    const int boff = (wn * 32 + fr) * 128 + swz;

    auto loadA = [&](const char* cA, int mh, int kk, bf16x8 (&af)[4]) {
        const int base = mh * 16384 + aoff;
#pragma unroll
        for (int mi = 0; mi < 4; ++mi)
            af[mi] = *(const bf16x8*)(cA + ((base + mi * 2048) ^ (kk << 6)));
    };
    auto loadB = [&](const char* cB, bf16x8 (&bf)[4][2]) {
#pragma unroll
        for (int nh = 0; nh < 2; ++nh)
#pragma unroll
            for (int ni2 = 0; ni2 < 2; ++ni2) {
                const int base = nh * 16384 + boff + ni2 * 2048;
                bf[nh * 2 + ni2][0] = *(const bf16x8*)(cB + base);
                bf[nh * 2 + ni2][1] = *(const bf16x8*)(cB + (base ^ 64));
            }
    };

    f32x4 acc[8][4] = {};

    auto mfma16 = [&](int mh, int kk, const bf16x8 (&af)[4], const bf16x8 (&bf)[4][2]) {
        __builtin_amdgcn_s_setprio(1);
#pragma unroll
        for (int mi = 0; mi < 4; ++mi)
#pragma unroll
            for (int ni = 0; ni < 4; ++ni)
                acc[mh * 4 + mi][ni] = __builtin_amdgcn_mfma_f32_16x16x32_bf16(
                    af[mi], bf[ni][kk], acc[mh * 4 + mi][ni], 0, 0, 0);
        __builtin_amdgcn_s_setprio(0);
    };

    // prologue: tile 0 into buf0, consumption order B h0,h1 then A h0,h1
    stageB(ldsB0, 0, 0);
    stageB(ldsB0, 1, 0);
    stageA(ldsA0, 0, 0);
    stageA(ldsA0, 1, 0);
    asm volatile("s_waitcnt vmcnt(2)" ::: "memory");   // B-all + A-h0 resident
    __builtin_amdgcn_s_barrier();
    __builtin_amdgcn_sched_barrier(0);

    auto tile_body = [&](const char* cA, const char* cB, char* nA, char* nB,
                         bool pf, size_t kn) {
        bf16x8 bf[4][2], af[4];
        // ---- region 1: quadrants (mh0,k0), (mh0,k1)
        if (pf) stageB(nB, 0, kn);
        loadB(cB, bf);
        loadA(cA, 0, 0, af);
        mfma16(0, 0, af, bf);
        if (pf) stageB(nB, 1, kn);
        loadA(cA, 0, 1, af);
        mfma16(0, 1, af, bf);
        if (pf) asm volatile("s_waitcnt vmcnt(4)" ::: "memory");
        else    asm volatile("s_waitcnt vmcnt(0)" ::: "memory");
        __builtin_amdgcn_s_barrier();
        __builtin_amdgcn_sched_barrier(0);
        // ---- region 2: quadrants (mh1,k0), (mh1,k1)
        if (pf) stageA(nA, 0, kn);
        loadA(cA, 1, 0, af);
        mfma16(1, 0, af, bf);
        if (pf) stageA(nA, 1, kn);
        loadA(cA, 1, 1, af);
        mfma16(1, 1, af, bf);
        if (pf) asm volatile("s_waitcnt vmcnt(2)" ::: "memory");
        else    asm volatile("s_waitcnt vmcnt(0)" ::: "memory");
        __builtin_amdgcn_s_barrier();
        __builtin_amdgcn_sched_barrier(0);
    };

    for (int t = 0; t < NT; t += 2) {
        tile_body(ldsA0, ldsB0, ldsA1, ldsB1, true,       (size_t)(t + 1) * BK);
        tile_body(ldsA1, ldsB1, ldsA0, ldsB0, t + 2 < NT, (size_t)(t + 2) * BK);
    }

    // epilogue: D[m=(lane>>4)*4+reg][n=lane&15] (verified m89/m91 mapping)
    const int cn = lane & 15;
    const int rq = (lane >> 4) * 4;
#pragma unroll
    for (int ni = 0; ni < 4; ++ni) {
        const int n = bn + wn * 64 + ni * 16 + cn;
        const float bv = bias[n];
#pragma unroll
        for (int mi = 0; mi < 8; ++mi) {
#pragma unroll
            for (int r = 0; r < 4; ++r) {
                const int m = bm + wm * 128 + mi * 16 + rq + r;
                C[(size_t)m * N + n] = acc[mi][ni][r] + bv;
            }
        }
    }
}

extern "C" void kernel_launch(void* const* d_in, const int* in_sizes, int n_in,
                              void* d_out, int out_size, void* d_ws, size_t ws_size,
                              hipStream_t stream)
{
    const float* x      = (const float*)d_in[0];   // 2*2048*4096 fp32
    const int*   qw     = (const int*)d_in[1];     // 16384*4096 int32
    const float* absmax = (const float*)d_in[2];   // 16384 fp32
    const float* code   = (const float*)d_in[3];   // 256 fp32
    const float* bias   = (const float*)d_in[4];   // 16384 fp32
    float* out = (float*)d_out;                    // 4096 x 16384 fp32

    // workspace: W_bf16 (N*K*2 = 128 MB) then x_bf16 (M*K*2 = 32 MB)
    __bf16* Wb = (__bf16*)d_ws;
    __bf16* Xb = (__bf16*)((char*)d_ws + (size_t)N * K * sizeof(__bf16));

    static bool attr_set = false;
    if (!attr_set) {
        (void)hipFuncSetAttribute((const void*)gemm_bt_bias,
                                  hipFuncAttributeMaxDynamicSharedMemorySize, LDS_BYTES);
        attr_set = true;
    }

    // dequant: 8.4M threads flat (32768 blocks); cvt: 2.1M threads flat (8192)
    dequant_w<<<(int)((size_t)N * K / 8 / 256), 256, 0, stream>>>(
        (const int4*)qw, code, absmax, (bf16x8*)Wb);
    cvt_x<<<(int)((size_t)M * K / 8 / 256), 256, 0, stream>>>(
        (const float4*)x, (bf16x8*)Xb);

    // GEMM: 16*64 = 1024 blocks, 512 threads, 128 KiB dynamic LDS
    gemm_bt_bias<<<dim3((M / BM) * (N / BN)), dim3(512), LDS_BYTES, stream>>>(
        Xb, Wb, bias, out);
}